// Round 1
// baseline (71.420 us; speedup 1.0000x reference)
//
#include <hip/hip_runtime.h>
#include <math.h>

namespace {
constexpr int kDim = 2048;
constexpr int kH = 16;
constexpr int kD = 128;
constexpr int kS = 8192;
constexpr int kChunk = 256;
constexpr int kNChunk = kS / kChunk; // 32
constexpr float kScale = 0.08838834764831843f; // 1/sqrt(128)
} // namespace

// One wave per output row: row = wave_id. Rows [0,2048)=w_q, [2048,4096)=w_k, [4096,6144)=w_v.
__global__ __launch_bounds__(256) void qkv_gemv(
    const float* __restrict__ x, const float* __restrict__ wq,
    const float* __restrict__ wk, const float* __restrict__ wv,
    float* __restrict__ qkv)
{
    const int wid  = (blockIdx.x << 2) | ((int)threadIdx.x >> 6);
    const int lane = threadIdx.x & 63;
    const float* W;
    int r = wid;
    if (r < kDim)            { W = wq; }
    else if (r < 2 * kDim)   { W = wk; r -= kDim; }
    else                     { W = wv; r -= 2 * kDim; }
    const float4* wrow = reinterpret_cast<const float4*>(W + (size_t)r * kDim);
    const float4* x4   = reinterpret_cast<const float4*>(x);
    float acc = 0.f;
#pragma unroll
    for (int k = 0; k < kDim / (4 * 64); ++k) {  // 8 iters, float4 per lane
        float4 w4 = wrow[(k << 6) + lane];
        float4 xv = x4[(k << 6) + lane];
        acc += w4.x * xv.x + w4.y * xv.y + w4.z * xv.z + w4.w * xv.w;
    }
#pragma unroll
    for (int off = 32; off; off >>= 1) acc += __shfl_xor(acc, off, 64);
    if (lane == 0) qkv[wid] = acc;
}

// Flash-decoding split-K: one block per (head, chunk). 4 waves, each wave one key/iter.
__global__ __launch_bounds__(256) void attn_partial(
    const float* __restrict__ k_cache, const float* __restrict__ v_cache,
    const float* __restrict__ qkv, const int* __restrict__ pos_p,
    float* __restrict__ part)
{
    const int h     = blockIdx.x >> 5;      // / kNChunk
    const int chunk = blockIdx.x & 31;      // % kNChunk
    const int wave  = threadIdx.x >> 6;
    const int lane  = threadIdx.x & 63;
    const int pos   = pos_p[0];

    const float2 q2 = reinterpret_cast<const float2*>(qkv + h * kD)[lane];

    float m = -INFINITY, l = 0.f;
    float ax = 0.f, ay = 0.f;

    const int s0    = chunk * kChunk;
    const int s_end = min(s0 + kChunk, pos);   // cached keys only (s == pos handled below)
    const size_t head_off = (size_t)h * kD;

#pragma unroll 4
    for (int s = s0 + wave; s < s_end; s += 4) {
        const float2* kp = reinterpret_cast<const float2*>(k_cache + (size_t)s * kH * kD + head_off);
        const float2* vp = reinterpret_cast<const float2*>(v_cache + (size_t)s * kH * kD + head_off);
        float2 k2 = kp[lane];
        float2 v2 = vp[lane];
        float d2 = q2.x * k2.x + q2.y * k2.y;
#pragma unroll
        for (int off = 32; off; off >>= 1) d2 += __shfl_xor(d2, off, 64);
        float sc = d2 * kScale;
        float mn = fmaxf(m, sc);
        float f  = __expf(m - mn);
        float p  = __expf(sc - mn);
        l  = l * f + p;
        ax = ax * f + p * v2.x;
        ay = ay * f + p * v2.y;
        m  = mn;
    }

    // New token's K/V (computed by qkv_gemv) — processed by the owning wave.
    if (pos >= s0 && pos < s0 + kChunk && wave == ((pos - s0) & 3)) {
        float2 k2 = reinterpret_cast<const float2*>(qkv + kDim     + h * kD)[lane];
        float2 v2 = reinterpret_cast<const float2*>(qkv + 2 * kDim + h * kD)[lane];
        float d2 = q2.x * k2.x + q2.y * k2.y;
#pragma unroll
        for (int off = 32; off; off >>= 1) d2 += __shfl_xor(d2, off, 64);
        float sc = d2 * kScale;
        float mn = fmaxf(m, sc);
        float f  = __expf(m - mn);
        float p  = __expf(sc - mn);
        l  = l * f + p;
        ax = ax * f + p * v2.x;
        ay = ay * f + p * v2.y;
        m  = mn;
    }

    __shared__ float sm[4], sl[4], sacc[4][kD];
    sacc[wave][2 * lane]     = ax;
    sacc[wave][2 * lane + 1] = ay;
    if (lane == 0) { sm[wave] = m; sl[wave] = l; }
    __syncthreads();

    if (wave == 0) {
        float M = fmaxf(fmaxf(sm[0], sm[1]), fmaxf(sm[2], sm[3]));
        float L = 0.f, ox = 0.f, oy = 0.f;
#pragma unroll
        for (int w = 0; w < 4; ++w) {
            if (sl[w] > 0.f) {
                float f = __expf(sm[w] - M);
                L  += sl[w] * f;
                ox += sacc[w][2 * lane] * f;
                oy += sacc[w][2 * lane + 1] * f;
            }
        }
        float* pp = part + (size_t)(h * kNChunk + chunk) * (kD + 2);
        reinterpret_cast<float2*>(pp)[lane] = make_float2(ox, oy);
        if (lane == 0) { pp[kD] = M; pp[kD + 1] = L; }
    }
}

// Combine split-K partials: one block per head, one thread per dim.
__global__ __launch_bounds__(128) void combine_partials(
    const float* __restrict__ part, float* __restrict__ o_out)
{
    const int h = blockIdx.x;
    const int d = threadIdx.x;
    float M = -INFINITY, L = 0.f, O = 0.f;
    for (int c = 0; c < kNChunk; ++c) {
        const float* pp = part + (size_t)(h * kNChunk + c) * (kD + 2);
        float mc = pp[kD], lc = pp[kD + 1];
        if (lc <= 0.f) continue;
        float Mn = fmaxf(M, mc);
        float f0 = __expf(M - Mn);
        float f1 = __expf(mc - Mn);
        O = O * f0 + pp[d] * f1;
        L = L * f0 + lc * f1;
        M = Mn;
    }
    o_out[h * kD + d] = O / L;
}

// Output projection GEMV: one wave per output row.
__global__ __launch_bounds__(256) void out_gemv(
    const float* __restrict__ o, const float* __restrict__ wo,
    float* __restrict__ out)
{
    const int wid  = (blockIdx.x << 2) | ((int)threadIdx.x >> 6);
    const int lane = threadIdx.x & 63;
    const float4* wrow = reinterpret_cast<const float4*>(wo + (size_t)wid * kDim);
    const float4* x4   = reinterpret_cast<const float4*>(o);
    float acc = 0.f;
#pragma unroll
    for (int k = 0; k < kDim / (4 * 64); ++k) {
        float4 w4 = wrow[(k << 6) + lane];
        float4 xv = x4[(k << 6) + lane];
        acc += w4.x * xv.x + w4.y * xv.y + w4.z * xv.z + w4.w * xv.w;
    }
#pragma unroll
    for (int off = 32; off; off >>= 1) acc += __shfl_xor(acc, off, 64);
    if (lane == 0) out[wid] = acc;
}

extern "C" void kernel_launch(void* const* d_in, const int* in_sizes, int n_in,
                              void* d_out, int out_size, void* d_ws, size_t ws_size,
                              hipStream_t stream)
{
    const float* x       = (const float*)d_in[0];
    const float* k_cache = (const float*)d_in[1];
    const float* v_cache = (const float*)d_in[2];
    const float* wq      = (const float*)d_in[3];
    const float* wk      = (const float*)d_in[4];
    const float* wv      = (const float*)d_in[5];
    const float* wo      = (const float*)d_in[6];
    const int*   pos     = (const int*)d_in[7];
    float* out = (float*)d_out;

    float* ws    = (float*)d_ws;
    float* qkv   = ws;                                  // 3*2048 floats
    float* part  = ws + 3 * kDim;                       // 16*32*130 floats
    float* o_out = part + kH * kNChunk * (kD + 2);      // 2048 floats

    qkv_gemv<<<3 * kDim / 4, 256, 0, stream>>>(x, wq, wk, wv, qkv);
    attn_partial<<<kH * kNChunk, 256, 0, stream>>>(k_cache, v_cache, qkv, pos, part);
    combine_partials<<<kH, 128, 0, stream>>>(part, o_out);
    out_gemv<<<kDim / 4, 256, 0, stream>>>(o_out, wo, out);
}

// Round 2
// 68.843 us; speedup vs baseline: 1.0374x; 1.0374x over previous
//
#include <hip/hip_runtime.h>
#include <math.h>

namespace {
constexpr int kDim = 2048;
constexpr int kH = 16;
constexpr int kD = 128;
constexpr int kS = 8192;
constexpr int kChunk = 128;
constexpr int kNChunk = kS / kChunk; // 64
constexpr float kScale = 0.08838834764831843f; // 1/sqrt(128)
} // namespace

// One wave per output row: row = wave_id. Rows [0,2048)=w_q, [2048,4096)=w_k, [4096,6144)=w_v.
__global__ __launch_bounds__(256) void qkv_gemv(
    const float* __restrict__ x, const float* __restrict__ wq,
    const float* __restrict__ wk, const float* __restrict__ wv,
    float* __restrict__ qkv)
{
    const int wid  = (blockIdx.x << 2) | ((int)threadIdx.x >> 6);
    const int lane = threadIdx.x & 63;
    const float* W;
    int r = wid;
    if (r < kDim)            { W = wq; }
    else if (r < 2 * kDim)   { W = wk; r -= kDim; }
    else                     { W = wv; r -= 2 * kDim; }
    const float4* wrow = reinterpret_cast<const float4*>(W + (size_t)r * kDim);
    const float4* x4   = reinterpret_cast<const float4*>(x);
    float acc = 0.f;
#pragma unroll
    for (int k = 0; k < kDim / (4 * 64); ++k) {  // 8 iters, float4 per lane
        float4 w4 = wrow[(k << 6) + lane];
        float4 xv = x4[(k << 6) + lane];
        acc += w4.x * xv.x + w4.y * xv.y + w4.z * xv.z + w4.w * xv.w;
    }
#pragma unroll
    for (int off = 32; off; off >>= 1) acc += __shfl_xor(acc, off, 64);
    if (lane == 0) qkv[wid] = acc;
}

// Flash-decoding split-K: one block per (head, chunk), 4 waves.
// Half-wave key layout: lanes 0-31 hold key 2j (float4 of D each), lanes 32-63 key 2j+1.
// 8 keys (4 pairs) in flight per wave per iteration -> 8 outstanding float4 loads.
__global__ __launch_bounds__(256) void attn_partial(
    const float* __restrict__ k_cache, const float* __restrict__ v_cache,
    const float* __restrict__ qkv, const int* __restrict__ pos_p,
    float* __restrict__ part)
{
    const int h     = blockIdx.x >> 6;               // / kNChunk
    const int chunk = blockIdx.x & (kNChunk - 1);
    const int wave  = threadIdx.x >> 6;
    const int lane  = threadIdx.x & 63;
    const int half  = lane >> 5;
    const int l32   = lane & 31;
    const int pos   = pos_p[0];

    const float4 q4   = reinterpret_cast<const float4*>(qkv + h * kD)[l32];
    const float* knew = qkv + kDim + h * kD;
    const float* vnew = qkv + 2 * kDim + h * kD;

    float  m = -INFINITY, l = 0.f;
    float4 acc = make_float4(0.f, 0.f, 0.f, 0.f);

    const int s0 = chunk * kChunk + wave * 32;  // this wave's 32 contiguous keys

#pragma unroll
    for (int it = 0; it < 4; ++it) {
        const int kbase = s0 + it * 8;
        float4 kv[4], vv[4];
        bool valid[4];
#pragma unroll
        for (int j = 0; j < 4; ++j) {
            const int key = kbase + 2 * j + half;
            valid[j] = key <= pos;
            const float* kp = (key == pos) ? knew : (k_cache + (size_t)key * kDim + h * kD);
            const float* vp = (key == pos) ? vnew : (v_cache + (size_t)key * kDim + h * kD);
            kv[j] = reinterpret_cast<const float4*>(kp)[l32];
            vv[j] = reinterpret_cast<const float4*>(vp)[l32];
        }
        float sc[4];
#pragma unroll
        for (int j = 0; j < 4; ++j)
            sc[j] = kv[j].x * q4.x + kv[j].y * q4.y + kv[j].z * q4.z + kv[j].w * q4.w;
#pragma unroll
        for (int mask = 16; mask; mask >>= 1) {
#pragma unroll
            for (int j = 0; j < 4; ++j) sc[j] += __shfl_xor(sc[j], mask, 64);
        }
#pragma unroll
        for (int j = 0; j < 4; ++j) sc[j] = valid[j] ? sc[j] * kScale : -INFINITY;

        const float bm = fmaxf(fmaxf(sc[0], sc[1]), fmaxf(sc[2], sc[3]));
        const float mn = fmaxf(m, bm);
        if (mn > -INFINITY) {
            const float f  = (m > -INFINITY) ? __expf(m - mn) : 0.f;
            const float p0 = __expf(sc[0] - mn);
            const float p1 = __expf(sc[1] - mn);
            const float p2 = __expf(sc[2] - mn);
            const float p3 = __expf(sc[3] - mn);
            l = l * f + (p0 + p1) + (p2 + p3);
            acc.x = acc.x * f + p0 * vv[0].x + p1 * vv[1].x + p2 * vv[2].x + p3 * vv[3].x;
            acc.y = acc.y * f + p0 * vv[0].y + p1 * vv[1].y + p2 * vv[2].y + p3 * vv[3].y;
            acc.z = acc.z * f + p0 * vv[0].z + p1 * vv[1].z + p2 * vv[2].z + p3 * vv[3].z;
            acc.w = acc.w * f + p0 * vv[0].w + p1 * vv[1].w + p2 * vv[2].w + p3 * vv[3].w;
            m = mn;
        }
    }

    // Merge the two half-wave accumulators (different m,l per half).
    {
        const float mo = __shfl_xor(m, 32, 64);
        const float lo = __shfl_xor(l, 32, 64);
        float4 ao;
        ao.x = __shfl_xor(acc.x, 32, 64);
        ao.y = __shfl_xor(acc.y, 32, 64);
        ao.z = __shfl_xor(acc.z, 32, 64);
        ao.w = __shfl_xor(acc.w, 32, 64);
        const float M  = fmaxf(m, mo);
        const float f0 = (m  > -INFINITY) ? __expf(m  - M) : 0.f;
        const float f1 = (mo > -INFINITY) ? __expf(mo - M) : 0.f;
        l     = l * f0 + lo * f1;
        acc.x = acc.x * f0 + ao.x * f1;
        acc.y = acc.y * f0 + ao.y * f1;
        acc.z = acc.z * f0 + ao.z * f1;
        acc.w = acc.w * f0 + ao.w * f1;
        m = M;
    }

    // Cross-wave merge via LDS.
    __shared__ float  sm[4], sl[4];
    __shared__ float4 sacc[4][32];
    if (lane < 32) sacc[wave][l32] = acc;
    if (lane == 0) { sm[wave] = m; sl[wave] = l; }
    __syncthreads();

    if (wave == 0 && lane < 32) {
        const float M = fmaxf(fmaxf(sm[0], sm[1]), fmaxf(sm[2], sm[3]));
        float L = 0.f;
        float4 A = make_float4(0.f, 0.f, 0.f, 0.f);
#pragma unroll
        for (int w = 0; w < 4; ++w) {
            if (sl[w] > 0.f) {
                const float f = __expf(sm[w] - M);
                const float4 a = sacc[w][l32];
                L   += sl[w] * f;
                A.x += a.x * f; A.y += a.y * f; A.z += a.z * f; A.w += a.w * f;
            }
        }
        float* pp = part + (size_t)(h * kNChunk + chunk) * (kD + 2);
        reinterpret_cast<float4*>(pp)[l32] = A;
        if (l32 == 0) { pp[kD] = M; pp[kD + 1] = L; }
    }
}

// Combine split-K partials: one block per head, one thread per dim.
__global__ __launch_bounds__(128) void combine_partials(
    const float* __restrict__ part, float* __restrict__ o_out)
{
    const int h = blockIdx.x;
    const int d = threadIdx.x;
    float M = -INFINITY, L = 0.f, O = 0.f;
    for (int c = 0; c < kNChunk; ++c) {
        const float* pp = part + (size_t)(h * kNChunk + c) * (kD + 2);
        float mc = pp[kD], lc = pp[kD + 1];
        if (lc <= 0.f) continue;
        float Mn = fmaxf(M, mc);
        float f0 = (M > -INFINITY) ? __expf(M - Mn) : 0.f;
        float f1 = __expf(mc - Mn);
        O = O * f0 + pp[d] * f1;
        L = L * f0 + lc * f1;
        M = Mn;
    }
    o_out[h * kD + d] = O / L;
}

// Output projection GEMV: one wave per output row.
__global__ __launch_bounds__(256) void out_gemv(
    const float* __restrict__ o, const float* __restrict__ wo,
    float* __restrict__ out)
{
    const int wid  = (blockIdx.x << 2) | ((int)threadIdx.x >> 6);
    const int lane = threadIdx.x & 63;
    const float4* wrow = reinterpret_cast<const float4*>(wo + (size_t)wid * kDim);
    const float4* x4   = reinterpret_cast<const float4*>(o);
    float acc = 0.f;
#pragma unroll
    for (int k = 0; k < kDim / (4 * 64); ++k) {
        float4 w4 = wrow[(k << 6) + lane];
        float4 xv = x4[(k << 6) + lane];
        acc += w4.x * xv.x + w4.y * xv.y + w4.z * xv.z + w4.w * xv.w;
    }
#pragma unroll
    for (int off = 32; off; off >>= 1) acc += __shfl_xor(acc, off, 64);
    if (lane == 0) out[wid] = acc;
}

extern "C" void kernel_launch(void* const* d_in, const int* in_sizes, int n_in,
                              void* d_out, int out_size, void* d_ws, size_t ws_size,
                              hipStream_t stream)
{
    const float* x       = (const float*)d_in[0];
    const float* k_cache = (const float*)d_in[1];
    const float* v_cache = (const float*)d_in[2];
    const float* wq      = (const float*)d_in[3];
    const float* wk      = (const float*)d_in[4];
    const float* wv      = (const float*)d_in[5];
    const float* wo      = (const float*)d_in[6];
    const int*   pos     = (const int*)d_in[7];
    float* out = (float*)d_out;

    float* ws    = (float*)d_ws;
    float* qkv   = ws;                                  // 3*2048 floats
    float* part  = ws + 3 * kDim;                       // 16*64*130 floats
    float* o_out = part + kH * kNChunk * (kD + 2);      // 2048 floats

    qkv_gemv<<<3 * kDim / 4, 256, 0, stream>>>(x, wq, wk, wv, qkv);
    attn_partial<<<kH * kNChunk, 256, 0, stream>>>(k_cache, v_cache, qkv, pos, part);
    combine_partials<<<kH, 128, 0, stream>>>(part, o_out);
    out_gemv<<<kDim / 4, 256, 0, stream>>>(o_out, wo, out);
}

// Round 3
// 53.650 us; speedup vs baseline: 1.3312x; 1.2832x over previous
//
#include <hip/hip_runtime.h>
#include <math.h>

namespace {
constexpr int kDim = 2048;
constexpr int kH = 16;
constexpr int kD = 128;
constexpr int kS = 8192;
constexpr int kChunk = 128;            // keys per PV block
constexpr int kNChunk = kS / kChunk;   // 64
constexpr int kKeysA = 64;             // keys per scores block
constexpr float kScale = 0.08838834764831843f; // 1/sqrt(128)
} // namespace

// One wave per output row: row = wave_id. Rows [0,2048)=w_q, [2048,4096)=w_k, [4096,6144)=w_v.
__global__ __launch_bounds__(256) void qkv_gemv(
    const float* __restrict__ x, const float* __restrict__ wq,
    const float* __restrict__ wk, const float* __restrict__ wv,
    float* __restrict__ qkv)
{
    const int wid  = (blockIdx.x << 2) | ((int)threadIdx.x >> 6);
    const int lane = threadIdx.x & 63;
    const float* W;
    int r = wid;
    if (r < kDim)            { W = wq; }
    else if (r < 2 * kDim)   { W = wk; r -= kDim; }
    else                     { W = wv; r -= 2 * kDim; }
    const float4* wrow = reinterpret_cast<const float4*>(W + (size_t)r * kDim);
    const float4* x4   = reinterpret_cast<const float4*>(x);
    float4 wv4[8], xv4[8];
#pragma unroll
    for (int k = 0; k < 8; ++k) wv4[k] = wrow[(k << 6) + lane];
#pragma unroll
    for (int k = 0; k < 8; ++k) xv4[k] = x4[(k << 6) + lane];
    float acc = 0.f;
#pragma unroll
    for (int k = 0; k < 8; ++k)
        acc += wv4[k].x * xv4[k].x + wv4[k].y * xv4[k].y
             + wv4[k].z * xv4[k].z + wv4[k].w * xv4[k].w;
#pragma unroll
    for (int off = 32; off; off >>= 1) acc += __shfl_xor(acc, off, 64);
    if (lane == 0) qkv[wid] = acc;
}

// Pass A: scores[h][s] = scale * (q_h . K[s,h,:]).  Pure streaming, no softmax.
// Lane mapping: kq = lane>>2 (16 keys/wave), q = lane&3 (32-dim quad each).
__global__ __launch_bounds__(256) void scores_kernel(
    const float* __restrict__ k_cache, const float* __restrict__ qkv,
    const int* __restrict__ pos_p, float* __restrict__ scores)
{
    const int h    = blockIdx.x >> 7;          // 128 blocks per head
    const int cb   = blockIdx.x & 127;
    const int wave = threadIdx.x >> 6;
    const int lane = threadIdx.x & 63;
    const int kq   = lane >> 2;
    const int q    = lane & 3;
    const int pos  = pos_p[0];
    const int key  = cb * kKeysA + wave * 16 + kq;

    const float* kp = (key == pos) ? (qkv + kDim + h * kD)
                                   : (k_cache + (size_t)key * kDim + h * kD);
    const float4* k4 = reinterpret_cast<const float4*>(kp + q * 32);
    const float4* q4 = reinterpret_cast<const float4*>(qkv + h * kD + q * 32);

    float4 kv[8], qv[8];
#pragma unroll
    for (int i = 0; i < 8; ++i) kv[i] = k4[i];
#pragma unroll
    for (int i = 0; i < 8; ++i) qv[i] = q4[i];

    float s = 0.f;
#pragma unroll
    for (int i = 0; i < 8; ++i)
        s += kv[i].x * qv[i].x + kv[i].y * qv[i].y + kv[i].z * qv[i].z + kv[i].w * qv[i].w;
    s += __shfl_xor(s, 1, 64);
    s += __shfl_xor(s, 2, 64);
    if (q == 0)
        scores[h * kS + key] = (key <= pos) ? s * kScale : -INFINITY;
}

// Pass B: per (head, chunk of 128 keys): block max, e = exp(s-M) in LDS,
// then 16 independent V loads per lane, weighted accumulate, write partial.
__global__ __launch_bounds__(256) void pv_partial(
    const float* __restrict__ v_cache, const float* __restrict__ qkv,
    const float* __restrict__ scores, const int* __restrict__ pos_p,
    float* __restrict__ part)
{
    const int h     = blockIdx.x >> 6;
    const int chunk = blockIdx.x & (kNChunk - 1);
    const int wave  = threadIdx.x >> 6;
    const int lane  = threadIdx.x & 63;
    const int half  = lane >> 5;
    const int l32   = lane & 31;
    const int t     = threadIdx.x;
    const int pos   = pos_p[0];
    const int s0    = chunk * kChunk;

    __shared__ float e_lds[kChunk];
    __shared__ float wmax[4];
    __shared__ float4 sacc[4][32];

    float sc_t = (t < kChunk) ? scores[h * kS + s0 + t] : -INFINITY;
    float mx = sc_t;
#pragma unroll
    for (int m = 32; m; m >>= 1) mx = fmaxf(mx, __shfl_xor(mx, m, 64));
    if (lane == 0) wmax[wave] = mx;
    __syncthreads();
    const float M = fmaxf(fmaxf(wmax[0], wmax[1]), fmaxf(wmax[2], wmax[3]));
    if (t < kChunk) e_lds[t] = (M > -INFINITY) ? __expf(sc_t - M) : 0.f;
    __syncthreads();

    // PV: wave handles 32 consecutive keys; two keys/iter via wave halves.
    float4 v[16];
#pragma unroll
    for (int it = 0; it < 16; ++it) {
        const int key = s0 + wave * 32 + 2 * it + half;
        const float* vp = (key == pos) ? (qkv + 2 * kDim + h * kD)
                                       : (v_cache + (size_t)key * kDim + h * kD);
        v[it] = reinterpret_cast<const float4*>(vp)[l32];
    }
    float ev[16];
#pragma unroll
    for (int it = 0; it < 16; ++it)
        ev[it] = e_lds[wave * 32 + 2 * it + half];

    float4 acc = make_float4(0.f, 0.f, 0.f, 0.f);
#pragma unroll
    for (int it = 0; it < 16; ++it) {
        acc.x += ev[it] * v[it].x;
        acc.y += ev[it] * v[it].y;
        acc.z += ev[it] * v[it].z;
        acc.w += ev[it] * v[it].w;
    }
    acc.x += __shfl_xor(acc.x, 32, 64);
    acc.y += __shfl_xor(acc.y, 32, 64);
    acc.z += __shfl_xor(acc.z, 32, 64);
    acc.w += __shfl_xor(acc.w, 32, 64);

    if (half == 0) sacc[wave][l32] = acc;
    __syncthreads();

    if (wave == 0 && half == 0) {
        float4 A = sacc[0][l32];
        const float4 B = sacc[1][l32], C = sacc[2][l32], D = sacc[3][l32];
        A.x += B.x + C.x + D.x;
        A.y += B.y + C.y + D.y;
        A.z += B.z + C.z + D.z;
        A.w += B.w + C.w + D.w;
        // l = sum of e over the block's 128 keys
        float le = e_lds[l32] + e_lds[l32 + 32] + e_lds[l32 + 64] + e_lds[l32 + 96];
#pragma unroll
        for (int m = 16; m; m >>= 1) le += __shfl_xor(le, m, 64);
        float* pp = part + (size_t)(h * kNChunk + chunk) * (kD + 2);
        reinterpret_cast<float4*>(pp)[l32] = A;
        if (l32 == 0) { pp[kD] = M; pp[kD + 1] = le; }
    }
}

// Combine: one block per head. Stage per-chunk scale factors in LDS, then each
// thread d does 64 INDEPENDENT partial loads (no serial rescale chain).
__global__ __launch_bounds__(128) void combine_partials(
    const float* __restrict__ part, float* __restrict__ o_out)
{
    const int h = blockIdx.x;
    const int t = threadIdx.x;
    __shared__ float f_lds[kNChunk];
    __shared__ float Lg;

    float mc = -INFINITY, lc = 0.f;
    if (t < kNChunk) {
        const float* pp = part + (size_t)(h * kNChunk + t) * (kD + 2);
        mc = pp[kD];
        lc = pp[kD + 1];
    }
    if (t < 64) {  // wave 0 exactly
        float Mg = mc;
#pragma unroll
        for (int m = 32; m; m >>= 1) Mg = fmaxf(Mg, __shfl_xor(Mg, m, 64));
        const float f = (lc > 0.f) ? __expf(mc - Mg) : 0.f;
        f_lds[t] = f;
        float lf = lc * f;
#pragma unroll
        for (int m = 32; m; m >>= 1) lf += __shfl_xor(lf, m, 64);
        if (t == 0) Lg = lf;
    }
    __syncthreads();

    float O = 0.f;
    const float* base = part + (size_t)h * kNChunk * (kD + 2) + t;
#pragma unroll 8
    for (int c = 0; c < kNChunk; ++c)
        O += base[(size_t)c * (kD + 2)] * f_lds[c];
    o_out[h * kD + t] = O / Lg;
}

// Output projection GEMV: one wave per output row.
__global__ __launch_bounds__(256) void out_gemv(
    const float* __restrict__ o, const float* __restrict__ wo,
    float* __restrict__ out)
{
    const int wid  = (blockIdx.x << 2) | ((int)threadIdx.x >> 6);
    const int lane = threadIdx.x & 63;
    const float4* wrow = reinterpret_cast<const float4*>(wo + (size_t)wid * kDim);
    const float4* x4   = reinterpret_cast<const float4*>(o);
    float4 wv4[8], xv4[8];
#pragma unroll
    for (int k = 0; k < 8; ++k) wv4[k] = wrow[(k << 6) + lane];
#pragma unroll
    for (int k = 0; k < 8; ++k) xv4[k] = x4[(k << 6) + lane];
    float acc = 0.f;
#pragma unroll
    for (int k = 0; k < 8; ++k)
        acc += wv4[k].x * xv4[k].x + wv4[k].y * xv4[k].y
             + wv4[k].z * xv4[k].z + wv4[k].w * xv4[k].w;
#pragma unroll
    for (int off = 32; off; off >>= 1) acc += __shfl_xor(acc, off, 64);
    if (lane == 0) out[wid] = acc;
}

extern "C" void kernel_launch(void* const* d_in, const int* in_sizes, int n_in,
                              void* d_out, int out_size, void* d_ws, size_t ws_size,
                              hipStream_t stream)
{
    const float* x       = (const float*)d_in[0];
    const float* k_cache = (const float*)d_in[1];
    const float* v_cache = (const float*)d_in[2];
    const float* wq      = (const float*)d_in[3];
    const float* wk      = (const float*)d_in[4];
    const float* wv      = (const float*)d_in[5];
    const float* wo      = (const float*)d_in[6];
    const int*   pos     = (const int*)d_in[7];
    float* out = (float*)d_out;

    float* ws     = (float*)d_ws;
    float* qkv    = ws;                                   // 3*2048
    float* scores = qkv + 3 * kDim;                       // 16*8192
    float* part   = scores + kH * kS;                     // 16*64*130
    float* o_out  = part + kH * kNChunk * (kD + 2);       // 2048

    qkv_gemv<<<3 * kDim / 4, 256, 0, stream>>>(x, wq, wk, wv, qkv);
    scores_kernel<<<kH * (kS / kKeysA), 256, 0, stream>>>(k_cache, qkv, pos, scores);
    pv_partial<<<kH * kNChunk, 256, 0, stream>>>(v_cache, qkv, scores, pos, part);
    combine_partials<<<kH, 128, 0, stream>>>(part, o_out);
    out_gemv<<<kDim / 4, 256, 0, stream>>>(o_out, wo, out);
}